// Round 12
// baseline (124.180 us; speedup 1.0000x reference)
//
#include <hip/hip_runtime.h>
#include <math.h>

// Problem constants: N=50000, E=800000, IN=64, H=128, OUT=64, G=64
constexpr int HDIM = 128;
constexpr int GRAPHS = 64;
constexpr int OUTD = 64;
constexpr int BK_SHIFT = 7;            // bucket = dst >> 7 (128 nodes/bucket)
constexpr int BK_NODES = 1 << BK_SHIFT;
constexpr int BK_CAP   = 2560;         // max edges per bucket (mean 2048, +11 sigma)

typedef __attribute__((ext_vector_type(8))) short bf16x8;
typedef __attribute__((ext_vector_type(8))) unsigned short us8;
typedef __attribute__((ext_vector_type(4))) unsigned short us4;
typedef __attribute__((ext_vector_type(4))) float f32x4;

__device__ inline float bf2f(unsigned short u) {
  return __uint_as_float(((unsigned int)u) << 16);
}
__device__ inline unsigned short f2bf(float x) {
  unsigned int u = __float_as_uint(x);
  return (unsigned short)((u + 0x7FFF + ((u >> 16) & 1)) >> 16);  // RNE
}

__device__ inline void atomicMaxF(float* addr, float v) {
  if (v >= 0.0f) atomicMax((int*)addr, __float_as_int(v));
  else           atomicMin((unsigned int*)addr, __float_as_uint(v));
}

// ---------------- prep: pack 4 weights + convert x + zero gcnt + init pools ----------------
__device__ inline void pack_body(const float* __restrict__ W, unsigned short* __restrict__ P,
                                 int K, int tid) {
  int lane = tid & 63, frag = tid >> 6;
  int t = frag >> 3, ct = frag & 7;
  int kb = t * 32 + (lane >> 4) * 8;
  int col = ct * 16 + (lane & 15);
  us8 o;
#pragma unroll
  for (int i = 0; i < 8; i++) o[i] = f2bf(W[(size_t)(kb + i) * HDIM + col]);
  *(us8*)(P + (size_t)tid * 8) = o;
}

__global__ __launch_bounds__(256) void prep_k(
    const float* __restrict__ x, unsigned short* __restrict__ x_b, int nx4,
    const float* __restrict__ W1l, const float* __restrict__ W1r,
    const float* __restrict__ W2l, const float* __restrict__ W2r,
    unsigned short* w1l_p, unsigned short* w1r_p,
    unsigned short* w2l_p, unsigned short* w2r_p,
    int* __restrict__ gcnt, int nbk,
    float* __restrict__ gsum, float* __restrict__ gmax) {
  const int b = blockIdx.x, t = threadIdx.x;
  if (b < 4)        pack_body(W1l, w1l_p, 64,  b * 256 + t);
  else if (b < 8)   pack_body(W1r, w1r_p, 64,  (b - 4) * 256 + t);
  else if (b < 16)  pack_body(W2l, w2l_p, 128, (b - 8) * 256 + t);
  else if (b < 24)  pack_body(W2r, w2r_p, 128, (b - 16) * 256 + t);
  else if (b == 24) { for (int i = t; i < nbk; i += 256) gcnt[i] = 0; }
  else if (b == 25) {
    for (int i = t; i < GRAPHS * HDIM; i += 256) { gsum[i] = 0.0f; gmax[i] = -INFINITY; }
  } else {
    for (int i = (b - 26) * 256 + t; i < nx4; i += 256 * 256) {
      float4 v = ((const float4*)x)[i];
      us4 o = { f2bf(v.x), f2bf(v.y), f2bf(v.z), f2bf(v.w) };
      *((us4*)x_b + i) = o;
    }
  }
}

// ---------------- phase 1: radix-partition edges into dst-buckets (packed int) ----------------
__global__ __launch_bounds__(256) void partition_k(const int* __restrict__ src,
                                                   const int* __restrict__ dst,
                                                   int* __restrict__ gcnt,
                                                   int* __restrict__ ebuf,
                                                   int E, int nbk) {
  __shared__ int hist[512];
  __shared__ int lcur[512];
  __shared__ int rbase[512];
  const int t = threadIdx.x;
  int tile = (E + gridDim.x - 1) / gridDim.x;
  int e0 = blockIdx.x * tile;
  int e1 = min(E, e0 + tile);
  for (int i = t; i < 512; i += 256) { hist[i] = 0; lcur[i] = 0; }
  __syncthreads();
  for (int e = e0 + t; e < e1; e += 256)
    atomicAdd(&hist[dst[e] >> BK_SHIFT], 1);
  __syncthreads();
  for (int b = t; b < nbk; b += 256)
    if (hist[b] > 0) rbase[b] = atomicAdd(&gcnt[b], hist[b]);
  __syncthreads();
  for (int e = e0 + t; e < e1; e += 256) {
    int d = dst[e];
    int b = d >> BK_SHIFT;
    int slot = rbase[b] + atomicAdd(&lcur[b], 1);
    if (slot < BK_CAP)
      ebuf[(size_t)b * BK_CAP + slot] = ((d & (BK_NODES - 1)) << 20) | src[e];
  }
}

// ---------------- bucket-count scan (wave 0) + graph bounds (wave 1) ----------------
__global__ __launch_bounds__(128) void scan_bounds_k(const int* __restrict__ gcnt,
                                                     int* __restrict__ bbase, int B,
                                                     const int* __restrict__ batch,
                                                     int* __restrict__ gstart, int n) {
  const int t = threadIdx.x;
  if (t < 64) {
    const int lane = t;
    int carry = 0;
    for (int base = 0; base < B; base += 64) {
      int i = base + lane;
      int v = (i < B) ? gcnt[i] : 0;
      int incl = v;
#pragma unroll
      for (int d = 1; d < 64; d <<= 1) {
        int u = __shfl_up(incl, d, 64);
        if (lane >= d) incl += u;
      }
      if (i < B) bbase[i] = carry + incl - v;
      carry += __shfl(incl, 63, 64);
    }
    if (lane == 0) bbase[B] = carry;
  } else {
    int g = t - 64;  // 0..63
    int lo = 0, hi = n;
    while (lo < hi) {
      int mid = (lo + hi) >> 1;
      if (batch[mid] < g) lo = mid + 1; else hi = mid;
    }
    gstart[g] = lo;
    if (g == 0) gstart[GRAPHS] = n;
  }
}

// ---------------- phase 2: per-bucket perm + offs build (LDS-local, coalesced out) ----------------
__global__ __launch_bounds__(256) void perm_build_k(const int* __restrict__ ebuf,
                                                    const int* __restrict__ gcnt,
                                                    const int* __restrict__ bbase,
                                                    int* __restrict__ offs,
                                                    int* __restrict__ perm, int n) {
  __shared__ int st[BK_CAP];
  __shared__ int perm_st[BK_CAP];
  __shared__ int nh[BK_NODES];
  __shared__ int excl_s[BK_NODES];
  __shared__ int lc[BK_NODES];
  const int b = blockIdx.x;
  const int t = threadIdx.x;
  const int nodeBase = b << BK_SHIFT;
  const int cnt = min(gcnt[b], BK_CAP);
  const int bb = bbase[b];
  for (int i = t; i < BK_NODES; i += 256) nh[i] = 0;
  __syncthreads();
  for (int i = t; i < cnt; i += 256) {
    int e = ebuf[(size_t)b * BK_CAP + i];
    st[i] = e;
    atomicAdd(&nh[e >> 20], 1);
  }
  __syncthreads();
  if (t < 64) {
    int v0 = nh[t];
    int incl = v0;
#pragma unroll
    for (int d = 1; d < 64; d <<= 1) {
      int u = __shfl_up(incl, d, 64);
      if (t >= d) incl += u;
    }
    excl_s[t] = incl - v0;
    int tot0 = __shfl(incl, 63, 64);
    int v1 = nh[64 + t];
    int incl1 = v1;
#pragma unroll
    for (int d = 1; d < 64; d <<= 1) {
      int u = __shfl_up(incl1, d, 64);
      if (t >= d) incl1 += u;
    }
    excl_s[64 + t] = tot0 + incl1 - v1;
  }
  __syncthreads();
  for (int i = t; i < BK_NODES; i += 256) {
    int idx = nodeBase + i;
    if (idx <= n) offs[idx] = bb + excl_s[i];
  }
  for (int i = t; i < BK_NODES; i += 256) lc[i] = excl_s[i];
  __syncthreads();
  for (int i = t; i < cnt; i += 256) {
    int e = st[i];
    int slot = atomicAdd(&lc[e >> 20], 1);
    perm_st[slot] = e & 0xFFFFF;
  }
  __syncthreads();
  for (int i = t; i < cnt; i += 256) perm[bb + i] = perm_st[i];
}

// ---------------- fused SAGE layer: gather-mean -> LDS -> MFMA (-> optional fused pooling) ----
// ROWS rows/block, 256 thr. LDS A row stride K+24 ch. POOL: h never hits HBM; pooled in-kernel.
template<int K, int ROWS, bool POOL>
__global__ __launch_bounds__(256) void sage_fused_k(
    const unsigned short* __restrict__ feat,
    const int* __restrict__ offs, const int* __restrict__ perm,
    const unsigned short* __restrict__ B0, const unsigned short* __restrict__ B1,
    const float* __restrict__ bias, unsigned short* __restrict__ out,
    const int* __restrict__ batch, float* __restrict__ gsum, float* __restrict__ gmax,
    int n) {
  constexpr int NT = K / 32;
  constexpr int C8 = K / 8;          // threads per row in gather phase
  constexpr int SR = K + 24;         // LDS A row stride (ch)
  constexpr int RPP = 256 / C8;      // rows covered per gather pass
  constexpr int PASSES = (ROWS + RPP - 1) / RPP;
  constexpr int RT = ROWS / 16;      // row tiles
  constexpr int WPR = 4 / RT;        // waves per row tile
  constexpr int CTW = 8 / WPR;       // col tiles per wave
  constexpr int PSR = HDIM + 8;      // pool tile row stride (ch)
  __shared__ unsigned short a_lds[ROWS * SR];
  __shared__ int batch_s[ROWS];
  const int t = threadIdx.x;
  const int rowBase = blockIdx.x * ROWS;

  // ---- gather phase: mean over neighbors (8-way ILP), write LDS A-tile ----
#pragma unroll
  for (int p = 0; p < PASSES; p++) {
    int lr = p * RPP + t / C8;
    int c8 = t % C8;
    int row = rowBase + lr;
    if (lr < ROWS && row < n) {
      int s = offs[row], e = offs[row + 1];
      float acc[8] = {0.f, 0.f, 0.f, 0.f, 0.f, 0.f, 0.f, 0.f};
      const unsigned short* fb = feat + c8 * 8;
      int j = s;
      for (; j + 7 < e; j += 8) {
        int r0 = perm[j],     r1 = perm[j + 1], r2 = perm[j + 2], r3 = perm[j + 3];
        int r4 = perm[j + 4], r5 = perm[j + 5], r6 = perm[j + 6], r7 = perm[j + 7];
        us8 v0 = *(const us8*)(fb + (size_t)r0 * K);
        us8 v1 = *(const us8*)(fb + (size_t)r1 * K);
        us8 v2 = *(const us8*)(fb + (size_t)r2 * K);
        us8 v3 = *(const us8*)(fb + (size_t)r3 * K);
        us8 v4 = *(const us8*)(fb + (size_t)r4 * K);
        us8 v5 = *(const us8*)(fb + (size_t)r5 * K);
        us8 v6 = *(const us8*)(fb + (size_t)r6 * K);
        us8 v7 = *(const us8*)(fb + (size_t)r7 * K);
#pragma unroll
        for (int q = 0; q < 8; q++) {
          float s0 = (bf2f(v0[q]) + bf2f(v1[q])) + (bf2f(v2[q]) + bf2f(v3[q]));
          float s1 = (bf2f(v4[q]) + bf2f(v5[q])) + (bf2f(v6[q]) + bf2f(v7[q]));
          acc[q] += s0 + s1;
        }
      }
      for (; j + 3 < e; j += 4) {
        int r0 = perm[j], r1 = perm[j + 1], r2 = perm[j + 2], r3 = perm[j + 3];
        us8 v0 = *(const us8*)(fb + (size_t)r0 * K);
        us8 v1 = *(const us8*)(fb + (size_t)r1 * K);
        us8 v2 = *(const us8*)(fb + (size_t)r2 * K);
        us8 v3 = *(const us8*)(fb + (size_t)r3 * K);
#pragma unroll
        for (int q = 0; q < 8; q++)
          acc[q] += (bf2f(v0[q]) + bf2f(v1[q])) + (bf2f(v2[q]) + bf2f(v3[q]));
      }
      for (; j < e; j++) {
        int r = perm[j];
        us8 v = *(const us8*)(fb + (size_t)r * K);
#pragma unroll
        for (int q = 0; q < 8; q++) acc[q] += bf2f(v[q]);
      }
      float sc = 1.0f / fmaxf((float)(e - s), 1.0f);
      us8 o;
#pragma unroll
      for (int q = 0; q < 8; q++) o[q] = f2bf(acc[q] * sc);
      *(us8*)(a_lds + lr * SR + c8 * 8) = o;
    }
  }
  if (POOL && t < ROWS) {
    int row = rowBase + t;
    batch_s[t] = (row < n) ? batch[row] : -1;
  }
  __syncthreads();

  // ---- MFMA phase ----
  const int lane = t & 63;
  const int w = t >> 6;
  const int rh = w / WPR;            // row tile
  const int cw = w % WPR;            // col group
  const int row0 = rowBase + rh * 16;
  const int l16 = lane & 15, lhi = lane >> 4;
  f32x4 acc[CTW];
#pragma unroll
  for (int cc = 0; cc < CTW; cc++) acc[cc] = (f32x4){0.f, 0.f, 0.f, 0.f};
  const unsigned short* al = a_lds + (rh * 16 + l16) * SR + lhi * 8;
  const unsigned short* ag = feat + (size_t)min(row0 + l16, n - 1) * K + lhi * 8;
#pragma unroll
  for (int t2 = 0; t2 < NT; t2++) {
    bf16x8 afA = *(const bf16x8*)(al + t2 * 32);
    bf16x8 afS = *(const bf16x8*)(ag + t2 * 32);
#pragma unroll
    for (int cc = 0; cc < CTW; cc++) {
      int ct = cw * CTW + cc;
      bf16x8 b0 = *(const bf16x8*)(B0 + ((size_t)(t2 * 8 + ct) * 64 + lane) * 8);
      acc[cc] = __builtin_amdgcn_mfma_f32_16x16x32_bf16(afA, b0, acc[cc], 0, 0, 0);
      bf16x8 b1 = *(const bf16x8*)(B1 + ((size_t)(t2 * 8 + ct) * 64 + lane) * 8);
      acc[cc] = __builtin_amdgcn_mfma_f32_16x16x32_bf16(afS, b1, acc[cc], 0, 0, 0);
    }
  }

  if constexpr (!POOL) {
    // epilogue: bias + ELU + global store
#pragma unroll
    for (int cc = 0; cc < CTW; cc++) {
      int col = (cw * CTW + cc) * 16 + l16;
      float bs = bias[col];
#pragma unroll
      for (int i = 0; i < 4; i++) {
        int row = row0 + lhi * 4 + i;
        if (row < n) {
          float v = acc[cc][i] + bs;
          v = (v > 0.f) ? v : expm1f(v);
          out[(size_t)row * HDIM + col] = f2bf(v);
        }
      }
    }
  } else {
    // epilogue: bias + ELU into reused LDS pool tile, then segmented per-graph reduce
    __syncthreads();  // all a_lds MFMA reads complete before overwrite
    unsigned short* ptile = a_lds;  // [ROWS][PSR], fits in a_lds for K=128
#pragma unroll
    for (int cc = 0; cc < CTW; cc++) {
      int col = (cw * CTW + cc) * 16 + l16;
      float bs = bias[col];
#pragma unroll
      for (int i = 0; i < 4; i++) {
        int rl = rh * 16 + lhi * 4 + i;
        float v = acc[cc][i] + bs;
        v = (v > 0.f) ? v : expm1f(v);
        ptile[rl * PSR + col] = f2bf(v);
      }
    }
    __syncthreads();
    // pool scan: thread (c = t&127, half = t>>7) scans ROWS/2 rows of its channel
    int c = t & 127;
    int half = t >> 7;
    float sum = 0.0f, mx = -INFINITY;
    int gc = -1;
    for (int r = half * (ROWS / 2); r < (half + 1) * (ROWS / 2); r++) {
      int g = batch_s[r];
      if (g < 0) continue;
      float v = bf2f(ptile[r * PSR + c]);
      if (g != gc) {
        if (gc >= 0) {
          atomicAdd(&gsum[gc * HDIM + c], sum);
          atomicMaxF(&gmax[gc * HDIM + c], mx);
        }
        gc = g; sum = 0.0f; mx = -INFINITY;
      }
      sum += v;
      mx = fmaxf(mx, v);
    }
    if (gc >= 0) {
      atomicAdd(&gsum[gc * HDIM + c], sum);
      atomicMaxF(&gmax[gc * HDIM + c], mx);
    }
  }
}

// ---------------- MLP head (f32) ----------------
__global__ __launch_bounds__(128) void head_k(
    const float* __restrict__ gsum, const float* __restrict__ gmax,
    const int* __restrict__ gstart,
    const float* __restrict__ W3, const float* __restrict__ b3,
    const float* __restrict__ W4, const float* __restrict__ b4,
    float* __restrict__ out) {
  __shared__ float pool_s[HDIM];
  __shared__ float t1_s[HDIM];
  int g = blockIdx.x, c = threadIdx.x;
  float cntf = (float)(gstart[g + 1] - gstart[g]);
  float ic = 1.0f / fmaxf(cntf, 1.0f);
  pool_s[c] = gsum[g * HDIM + c] * ic + gmax[g * HDIM + c];
  __syncthreads();
  float acc = b3[c];
  for (int k = 0; k < HDIM; k++) acc += pool_s[k] * W3[k * HDIM + c];
  t1_s[c] = fmaxf(acc, 0.0f);
  __syncthreads();
  if (c < OUTD) {
    float acc2 = b4[c];
    for (int k = 0; k < HDIM; k++) acc2 += t1_s[k] * W4[k * OUTD + c];
    out[g * OUTD + c] = acc2;
  }
}

extern "C" void kernel_launch(void* const* d_in, const int* in_sizes, int n_in,
                              void* d_out, int out_size, void* d_ws, size_t ws_size,
                              hipStream_t stream) {
  const float* x     = (const float*)d_in[0];
  const int*   ei    = (const int*)d_in[1];
  const int*   batch = (const int*)d_in[2];
  const float* W1l = (const float*)d_in[3];
  const float* W1r = (const float*)d_in[4];
  const float* b1  = (const float*)d_in[5];
  const float* W2l = (const float*)d_in[6];
  const float* W2r = (const float*)d_in[7];
  const float* b2  = (const float*)d_in[8];
  const float* W3  = (const float*)d_in[9];
  const float* b3  = (const float*)d_in[10];
  const float* W4  = (const float*)d_in[11];
  const float* b4  = (const float*)d_in[12];

  const int N  = in_sizes[2];          // 50000
  const int E  = in_sizes[1] / 2;      // 800000
  const int IN = in_sizes[0] / N;      // 64
  const int* src = ei;
  const int* dst = ei + E;
  const int NBK = (N + BK_NODES - 1) / BK_NODES;  // 391 buckets

  // workspace layout
  char* ws = (char*)d_ws;
  size_t off = 0;
  auto alloc = [&](size_t bytes) { void* p = ws + off; off += (bytes + 255) & ~(size_t)255; return p; };
  int*  offs  = (int*)alloc((size_t)(N + 1) * 4);
  int*  perm  = (int*)alloc((size_t)E * 4);
  int*  gcnt  = (int*)alloc((size_t)NBK * 4);
  int*  bbase = (int*)alloc((size_t)(NBK + 1) * 4);
  int*  ebuf  = (int*)alloc((size_t)NBK * BK_CAP * 4);
  unsigned short* x_b   = (unsigned short*)alloc((size_t)N * IN * 2);
  unsigned short* h1_b  = (unsigned short*)alloc((size_t)N * HDIM * 2);
  unsigned short* w1l_p = (unsigned short*)alloc((size_t)IN * HDIM * 2);
  unsigned short* w1r_p = (unsigned short*)alloc((size_t)IN * HDIM * 2);
  unsigned short* w2l_p = (unsigned short*)alloc((size_t)HDIM * HDIM * 2);
  unsigned short* w2r_p = (unsigned short*)alloc((size_t)HDIM * HDIM * 2);
  float* gsum = (float*)alloc((size_t)GRAPHS * HDIM * 4);
  float* gmax = (float*)alloc((size_t)GRAPHS * HDIM * 4);
  int* gstart = (int*)alloc((size_t)(GRAPHS + 1) * 4);
  (void)ws_size; (void)n_in; (void)out_size;

  // ---- prep: pack weights + convert x + zero gcnt + init pools (one launch) ----
  prep_k<<<282, 256, 0, stream>>>(x, x_b, N * IN / 4, W1l, W1r, W2l, W2r,
                                  w1l_p, w1r_p, w2l_p, w2r_p, gcnt, NBK, gsum, gmax);

  // ---- build CSR via radix partition + graph bounds ----
  partition_k<<<256, 256, 0, stream>>>(src, dst, gcnt, ebuf, E, NBK);
  scan_bounds_k<<<1, 128, 0, stream>>>(gcnt, bbase, NBK, batch, gstart, N);
  perm_build_k<<<NBK, 256, 0, stream>>>(ebuf, gcnt, bbase, offs, perm, N);

  // ----- layer 1 (fused gather + GEMM): h1 = elu(mean(x_nbr)@W1l + x@W1r + b1) -----
  sage_fused_k<64, 32, false><<<(N + 31) / 32, 256, 0, stream>>>(
      x_b, offs, perm, w1l_p, w1r_p, b1, h1_b, nullptr, nullptr, nullptr, N);

  // ----- layer 2 + fused pooling (h2 never leaves the CU) -----
  sage_fused_k<128, 32, true><<<(N + 31) / 32, 256, 0, stream>>>(
      h1_b, offs, perm, w2l_p, w2r_p, b2, nullptr, batch, gsum, gmax, N);

  // ----- head -----
  head_k<<<GRAPHS, 128, 0, stream>>>(gsum, gmax, gstart, W3, b3, W4, b4, (float*)d_out);
}

// Round 13
// 115.162 us; speedup vs baseline: 1.0783x; 1.0783x over previous
//
#include <hip/hip_runtime.h>
#include <math.h>

// Problem constants: N=50000, E=800000, IN=64, H=128, OUT=64, G=64
constexpr int HDIM = 128;
constexpr int GRAPHS = 64;
constexpr int OUTD = 64;
constexpr int BK_SHIFT = 7;            // bucket = dst >> 7 (128 nodes/bucket)
constexpr int BK_NODES = 1 << BK_SHIFT;
constexpr int BK_CAP   = 2560;         // max edges per bucket (mean 2048, +11 sigma)
constexpr int EBCAP    = 1536;         // max edges per 32-row block LDS stage (mean 512, +45 sigma)

typedef __attribute__((ext_vector_type(8))) short bf16x8;
typedef __attribute__((ext_vector_type(8))) unsigned short us8;
typedef __attribute__((ext_vector_type(4))) unsigned short us4;
typedef __attribute__((ext_vector_type(4))) float f32x4;

__device__ inline float bf2f(unsigned short u) {
  return __uint_as_float(((unsigned int)u) << 16);
}
__device__ inline unsigned short f2bf(float x) {
  unsigned int u = __float_as_uint(x);
  return (unsigned short)((u + 0x7FFF + ((u >> 16) & 1)) >> 16);  // RNE
}

__device__ inline void atomicMaxF(float* addr, float v) {
  if (v >= 0.0f) atomicMax((int*)addr, __float_as_int(v));
  else           atomicMin((unsigned int*)addr, __float_as_uint(v));
}

// ---------------- prep: pack 4 weights + convert x + zero gcnt + init pools ----------------
__device__ inline void pack_body(const float* __restrict__ W, unsigned short* __restrict__ P,
                                 int K, int tid) {
  int lane = tid & 63, frag = tid >> 6;
  int t = frag >> 3, ct = frag & 7;
  int kb = t * 32 + (lane >> 4) * 8;
  int col = ct * 16 + (lane & 15);
  us8 o;
#pragma unroll
  for (int i = 0; i < 8; i++) o[i] = f2bf(W[(size_t)(kb + i) * HDIM + col]);
  *(us8*)(P + (size_t)tid * 8) = o;
}

__global__ __launch_bounds__(256) void prep_k(
    const float* __restrict__ x, unsigned short* __restrict__ x_b, int nx4,
    const float* __restrict__ W1l, const float* __restrict__ W1r,
    const float* __restrict__ W2l, const float* __restrict__ W2r,
    unsigned short* w1l_p, unsigned short* w1r_p,
    unsigned short* w2l_p, unsigned short* w2r_p,
    int* __restrict__ gcnt, int nbk,
    float* __restrict__ gsum, float* __restrict__ gmax) {
  const int b = blockIdx.x, t = threadIdx.x;
  if (b < 4)        pack_body(W1l, w1l_p, 64,  b * 256 + t);
  else if (b < 8)   pack_body(W1r, w1r_p, 64,  (b - 4) * 256 + t);
  else if (b < 16)  pack_body(W2l, w2l_p, 128, (b - 8) * 256 + t);
  else if (b < 24)  pack_body(W2r, w2r_p, 128, (b - 16) * 256 + t);
  else if (b == 24) { for (int i = t; i < nbk; i += 256) gcnt[i] = 0; }
  else if (b == 25) {
    for (int i = t; i < GRAPHS * HDIM; i += 256) { gsum[i] = 0.0f; gmax[i] = -INFINITY; }
  } else {
    for (int i = (b - 26) * 256 + t; i < nx4; i += 256 * 256) {
      float4 v = ((const float4*)x)[i];
      us4 o = { f2bf(v.x), f2bf(v.y), f2bf(v.z), f2bf(v.w) };
      *((us4*)x_b + i) = o;
    }
  }
}

// ---------------- phase 1: radix-partition edges into dst-buckets (packed int) ----------------
__global__ __launch_bounds__(256) void partition_k(const int* __restrict__ src,
                                                   const int* __restrict__ dst,
                                                   int* __restrict__ gcnt,
                                                   int* __restrict__ ebuf,
                                                   int E, int nbk) {
  __shared__ int hist[512];
  __shared__ int lcur[512];
  __shared__ int rbase[512];
  const int t = threadIdx.x;
  int tile = (E + gridDim.x - 1) / gridDim.x;
  int e0 = blockIdx.x * tile;
  int e1 = min(E, e0 + tile);
  for (int i = t; i < 512; i += 256) { hist[i] = 0; lcur[i] = 0; }
  __syncthreads();
  for (int e = e0 + t; e < e1; e += 256)
    atomicAdd(&hist[dst[e] >> BK_SHIFT], 1);
  __syncthreads();
  for (int b = t; b < nbk; b += 256)
    if (hist[b] > 0) rbase[b] = atomicAdd(&gcnt[b], hist[b]);
  __syncthreads();
  for (int e = e0 + t; e < e1; e += 256) {
    int d = dst[e];
    int b = d >> BK_SHIFT;
    int slot = rbase[b] + atomicAdd(&lcur[b], 1);
    if (slot < BK_CAP)
      ebuf[(size_t)b * BK_CAP + slot] = ((d & (BK_NODES - 1)) << 20) | src[e];
  }
}

// ---------------- bucket-count scan (wave 0) + graph bounds (wave 1) ----------------
__global__ __launch_bounds__(128) void scan_bounds_k(const int* __restrict__ gcnt,
                                                     int* __restrict__ bbase, int B,
                                                     const int* __restrict__ batch,
                                                     int* __restrict__ gstart, int n) {
  const int t = threadIdx.x;
  if (t < 64) {
    const int lane = t;
    int carry = 0;
    for (int base = 0; base < B; base += 64) {
      int i = base + lane;
      int v = (i < B) ? gcnt[i] : 0;
      int incl = v;
#pragma unroll
      for (int d = 1; d < 64; d <<= 1) {
        int u = __shfl_up(incl, d, 64);
        if (lane >= d) incl += u;
      }
      if (i < B) bbase[i] = carry + incl - v;
      carry += __shfl(incl, 63, 64);
    }
    if (lane == 0) bbase[B] = carry;
  } else {
    int g = t - 64;  // 0..63
    int lo = 0, hi = n;
    while (lo < hi) {
      int mid = (lo + hi) >> 1;
      if (batch[mid] < g) lo = mid + 1; else hi = mid;
    }
    gstart[g] = lo;
    if (g == 0) gstart[GRAPHS] = n;
  }
}

// ---------------- phase 2: per-bucket perm + offs build (LDS-local, coalesced out) ----------------
__global__ __launch_bounds__(256) void perm_build_k(const int* __restrict__ ebuf,
                                                    const int* __restrict__ gcnt,
                                                    const int* __restrict__ bbase,
                                                    int* __restrict__ offs,
                                                    int* __restrict__ perm, int n) {
  __shared__ int st[BK_CAP];
  __shared__ int perm_st[BK_CAP];
  __shared__ int nh[BK_NODES];
  __shared__ int excl_s[BK_NODES];
  __shared__ int lc[BK_NODES];
  const int b = blockIdx.x;
  const int t = threadIdx.x;
  const int nodeBase = b << BK_SHIFT;
  const int cnt = min(gcnt[b], BK_CAP);
  const int bb = bbase[b];
  for (int i = t; i < BK_NODES; i += 256) nh[i] = 0;
  __syncthreads();
  for (int i = t; i < cnt; i += 256) {
    int e = ebuf[(size_t)b * BK_CAP + i];
    st[i] = e;
    atomicAdd(&nh[e >> 20], 1);
  }
  __syncthreads();
  if (t < 64) {
    int v0 = nh[t];
    int incl = v0;
#pragma unroll
    for (int d = 1; d < 64; d <<= 1) {
      int u = __shfl_up(incl, d, 64);
      if (t >= d) incl += u;
    }
    excl_s[t] = incl - v0;
    int tot0 = __shfl(incl, 63, 64);
    int v1 = nh[64 + t];
    int incl1 = v1;
#pragma unroll
    for (int d = 1; d < 64; d <<= 1) {
      int u = __shfl_up(incl1, d, 64);
      if (t >= d) incl1 += u;
    }
    excl_s[64 + t] = tot0 + incl1 - v1;
  }
  __syncthreads();
  for (int i = t; i < BK_NODES; i += 256) {
    int idx = nodeBase + i;
    if (idx <= n) offs[idx] = bb + excl_s[i];
  }
  for (int i = t; i < BK_NODES; i += 256) lc[i] = excl_s[i];
  __syncthreads();
  for (int i = t; i < cnt; i += 256) {
    int e = st[i];
    int slot = atomicAdd(&lc[e >> 20], 1);
    perm_st[slot] = e & 0xFFFFF;
  }
  __syncthreads();
  for (int i = t; i < cnt; i += 256) perm[bb + i] = perm_st[i];
}

// ---------------- fused SAGE layer: gather-mean -> LDS -> MFMA (-> optional fused pooling) ----
// ROWS rows/block, 256 thr. Block's perm slice staged in LDS (contiguous). 4-way ILP gather.
template<int K, int ROWS, bool POOL>
__global__ __launch_bounds__(256) void sage_fused_k(
    const unsigned short* __restrict__ feat,
    const int* __restrict__ offs, const int* __restrict__ perm,
    const unsigned short* __restrict__ B0, const unsigned short* __restrict__ B1,
    const float* __restrict__ bias, unsigned short* __restrict__ out,
    const int* __restrict__ batch, float* __restrict__ gsum, float* __restrict__ gmax,
    int n) {
  constexpr int NT = K / 32;
  constexpr int C8 = K / 8;          // threads per row in gather phase
  constexpr int SR = K + 24;         // LDS A row stride (ch)
  constexpr int RPP = 256 / C8;      // rows covered per gather pass
  constexpr int PASSES = (ROWS + RPP - 1) / RPP;
  constexpr int RT = ROWS / 16;      // row tiles
  constexpr int WPR = 4 / RT;        // waves per row tile
  constexpr int CTW = 8 / WPR;       // col tiles per wave
  constexpr int PSR = HDIM + 8;      // pool tile row stride (ch)
  __shared__ unsigned short a_lds[ROWS * SR];
  __shared__ int perm_s[EBCAP];
  __shared__ int batch_s[ROWS];
  const int t = threadIdx.x;
  const int rowBase = blockIdx.x * ROWS;

  // ---- stage this block's contiguous perm slice into LDS ----
  const int rowEnd = min(rowBase + ROWS, n);
  const int ebase = offs[rowBase];
  const int ecount = offs[rowEnd] - ebase;
  for (int i = t; i < min(ecount, EBCAP); i += 256) perm_s[i] = perm[ebase + i];
  if (POOL && t < ROWS) {
    int row = rowBase + t;
    batch_s[t] = (row < n) ? batch[row] : -1;
  }
  __syncthreads();

  // ---- gather phase: mean over neighbors (4-way ILP, indices from LDS) ----
  auto gather_all = [&](auto idxAt) {
#pragma unroll
    for (int p = 0; p < PASSES; p++) {
      int lr = p * RPP + t / C8;
      int c8 = t % C8;
      int row = rowBase + lr;
      if (lr < ROWS && row < n) {
        int s = offs[row], e = offs[row + 1];
        float acc[8] = {0.f, 0.f, 0.f, 0.f, 0.f, 0.f, 0.f, 0.f};
        const unsigned short* fb = feat + c8 * 8;
        int j = s;
        for (; j + 3 < e; j += 4) {
          int r0 = idxAt(j), r1 = idxAt(j + 1), r2 = idxAt(j + 2), r3 = idxAt(j + 3);
          us8 v0 = *(const us8*)(fb + (size_t)r0 * K);
          us8 v1 = *(const us8*)(fb + (size_t)r1 * K);
          us8 v2 = *(const us8*)(fb + (size_t)r2 * K);
          us8 v3 = *(const us8*)(fb + (size_t)r3 * K);
#pragma unroll
          for (int q = 0; q < 8; q++)
            acc[q] += (bf2f(v0[q]) + bf2f(v1[q])) + (bf2f(v2[q]) + bf2f(v3[q]));
        }
        for (; j < e; j++) {
          int r = idxAt(j);
          us8 v = *(const us8*)(fb + (size_t)r * K);
#pragma unroll
          for (int q = 0; q < 8; q++) acc[q] += bf2f(v[q]);
        }
        float sc = 1.0f / fmaxf((float)(e - s), 1.0f);
        us8 o;
#pragma unroll
        for (int q = 0; q < 8; q++) o[q] = f2bf(acc[q] * sc);
        *(us8*)(a_lds + lr * SR + c8 * 8) = o;
      }
    }
  };
  if (ecount <= EBCAP) gather_all([&](int j) { return perm_s[j - ebase]; });
  else                 gather_all([&](int j) { return perm[j]; });
  __syncthreads();

  // ---- MFMA phase ----
  const int lane = t & 63;
  const int w = t >> 6;
  const int rh = w / WPR;            // row tile
  const int cw = w % WPR;            // col group
  const int row0 = rowBase + rh * 16;
  const int l16 = lane & 15, lhi = lane >> 4;
  f32x4 acc[CTW];
#pragma unroll
  for (int cc = 0; cc < CTW; cc++) acc[cc] = (f32x4){0.f, 0.f, 0.f, 0.f};
  const unsigned short* al = a_lds + (rh * 16 + l16) * SR + lhi * 8;
  const unsigned short* ag = feat + (size_t)min(row0 + l16, n - 1) * K + lhi * 8;
#pragma unroll
  for (int t2 = 0; t2 < NT; t2++) {
    bf16x8 afA = *(const bf16x8*)(al + t2 * 32);
    bf16x8 afS = *(const bf16x8*)(ag + t2 * 32);
#pragma unroll
    for (int cc = 0; cc < CTW; cc++) {
      int ct = cw * CTW + cc;
      bf16x8 b0 = *(const bf16x8*)(B0 + ((size_t)(t2 * 8 + ct) * 64 + lane) * 8);
      acc[cc] = __builtin_amdgcn_mfma_f32_16x16x32_bf16(afA, b0, acc[cc], 0, 0, 0);
      bf16x8 b1 = *(const bf16x8*)(B1 + ((size_t)(t2 * 8 + ct) * 64 + lane) * 8);
      acc[cc] = __builtin_amdgcn_mfma_f32_16x16x32_bf16(afS, b1, acc[cc], 0, 0, 0);
    }
  }

  if constexpr (!POOL) {
    // epilogue: bias + ELU + global store
#pragma unroll
    for (int cc = 0; cc < CTW; cc++) {
      int col = (cw * CTW + cc) * 16 + l16;
      float bs = bias[col];
#pragma unroll
      for (int i = 0; i < 4; i++) {
        int row = row0 + lhi * 4 + i;
        if (row < n) {
          float v = acc[cc][i] + bs;
          v = (v > 0.f) ? v : expm1f(v);
          out[(size_t)row * HDIM + col] = f2bf(v);
        }
      }
    }
  } else {
    // epilogue: bias + ELU into reused LDS pool tile, then segmented per-graph reduce
    __syncthreads();  // all a_lds MFMA reads complete before overwrite
    unsigned short* ptile = a_lds;  // [ROWS][PSR], fits in a_lds for K=128
#pragma unroll
    for (int cc = 0; cc < CTW; cc++) {
      int col = (cw * CTW + cc) * 16 + l16;
      float bs = bias[col];
#pragma unroll
      for (int i = 0; i < 4; i++) {
        int rl = rh * 16 + lhi * 4 + i;
        float v = acc[cc][i] + bs;
        v = (v > 0.f) ? v : expm1f(v);
        ptile[rl * PSR + col] = f2bf(v);
      }
    }
    __syncthreads();
    // pool scan: thread (c = t&127, half = t>>7) scans ROWS/2 rows of its channel
    int c = t & 127;
    int half = t >> 7;
    float sum = 0.0f, mx = -INFINITY;
    int gc = -1;
    for (int r = half * (ROWS / 2); r < (half + 1) * (ROWS / 2); r++) {
      int g = batch_s[r];
      if (g < 0) continue;
      float v = bf2f(ptile[r * PSR + c]);
      if (g != gc) {
        if (gc >= 0) {
          atomicAdd(&gsum[gc * HDIM + c], sum);
          atomicMaxF(&gmax[gc * HDIM + c], mx);
        }
        gc = g; sum = 0.0f; mx = -INFINITY;
      }
      sum += v;
      mx = fmaxf(mx, v);
    }
    if (gc >= 0) {
      atomicAdd(&gsum[gc * HDIM + c], sum);
      atomicMaxF(&gmax[gc * HDIM + c], mx);
    }
  }
}

// ---------------- MLP head (f32) ----------------
__global__ __launch_bounds__(128) void head_k(
    const float* __restrict__ gsum, const float* __restrict__ gmax,
    const int* __restrict__ gstart,
    const float* __restrict__ W3, const float* __restrict__ b3,
    const float* __restrict__ W4, const float* __restrict__ b4,
    float* __restrict__ out) {
  __shared__ float pool_s[HDIM];
  __shared__ float t1_s[HDIM];
  int g = blockIdx.x, c = threadIdx.x;
  float cntf = (float)(gstart[g + 1] - gstart[g]);
  float ic = 1.0f / fmaxf(cntf, 1.0f);
  pool_s[c] = gsum[g * HDIM + c] * ic + gmax[g * HDIM + c];
  __syncthreads();
  float acc = b3[c];
  for (int k = 0; k < HDIM; k++) acc += pool_s[k] * W3[k * HDIM + c];
  t1_s[c] = fmaxf(acc, 0.0f);
  __syncthreads();
  if (c < OUTD) {
    float acc2 = b4[c];
    for (int k = 0; k < HDIM; k++) acc2 += t1_s[k] * W4[k * OUTD + c];
    out[g * OUTD + c] = acc2;
  }
}

extern "C" void kernel_launch(void* const* d_in, const int* in_sizes, int n_in,
                              void* d_out, int out_size, void* d_ws, size_t ws_size,
                              hipStream_t stream) {
  const float* x     = (const float*)d_in[0];
  const int*   ei    = (const int*)d_in[1];
  const int*   batch = (const int*)d_in[2];
  const float* W1l = (const float*)d_in[3];
  const float* W1r = (const float*)d_in[4];
  const float* b1  = (const float*)d_in[5];
  const float* W2l = (const float*)d_in[6];
  const float* W2r = (const float*)d_in[7];
  const float* b2  = (const float*)d_in[8];
  const float* W3  = (const float*)d_in[9];
  const float* b3  = (const float*)d_in[10];
  const float* W4  = (const float*)d_in[11];
  const float* b4  = (const float*)d_in[12];

  const int N  = in_sizes[2];          // 50000
  const int E  = in_sizes[1] / 2;      // 800000
  const int IN = in_sizes[0] / N;      // 64
  const int* src = ei;
  const int* dst = ei + E;
  const int NBK = (N + BK_NODES - 1) / BK_NODES;  // 391 buckets

  // workspace layout
  char* ws = (char*)d_ws;
  size_t off = 0;
  auto alloc = [&](size_t bytes) { void* p = ws + off; off += (bytes + 255) & ~(size_t)255; return p; };
  int*  offs  = (int*)alloc((size_t)(N + 1) * 4);
  int*  perm  = (int*)alloc((size_t)E * 4);
  int*  gcnt  = (int*)alloc((size_t)NBK * 4);
  int*  bbase = (int*)alloc((size_t)(NBK + 1) * 4);
  int*  ebuf  = (int*)alloc((size_t)NBK * BK_CAP * 4);
  unsigned short* x_b   = (unsigned short*)alloc((size_t)N * IN * 2);
  unsigned short* h1_b  = (unsigned short*)alloc((size_t)N * HDIM * 2);
  unsigned short* w1l_p = (unsigned short*)alloc((size_t)IN * HDIM * 2);
  unsigned short* w1r_p = (unsigned short*)alloc((size_t)IN * HDIM * 2);
  unsigned short* w2l_p = (unsigned short*)alloc((size_t)HDIM * HDIM * 2);
  unsigned short* w2r_p = (unsigned short*)alloc((size_t)HDIM * HDIM * 2);
  float* gsum = (float*)alloc((size_t)GRAPHS * HDIM * 4);
  float* gmax = (float*)alloc((size_t)GRAPHS * HDIM * 4);
  int* gstart = (int*)alloc((size_t)(GRAPHS + 1) * 4);
  (void)ws_size; (void)n_in; (void)out_size;

  // ---- prep: pack weights + convert x + zero gcnt + init pools (one launch) ----
  prep_k<<<282, 256, 0, stream>>>(x, x_b, N * IN / 4, W1l, W1r, W2l, W2r,
                                  w1l_p, w1r_p, w2l_p, w2r_p, gcnt, NBK, gsum, gmax);

  // ---- build CSR via radix partition + graph bounds ----
  partition_k<<<256, 256, 0, stream>>>(src, dst, gcnt, ebuf, E, NBK);
  scan_bounds_k<<<1, 128, 0, stream>>>(gcnt, bbase, NBK, batch, gstart, N);
  perm_build_k<<<NBK, 256, 0, stream>>>(ebuf, gcnt, bbase, offs, perm, N);

  // ----- layer 1 (fused gather + GEMM): h1 = elu(mean(x_nbr)@W1l + x@W1r + b1) -----
  sage_fused_k<64, 32, false><<<(N + 31) / 32, 256, 0, stream>>>(
      x_b, offs, perm, w1l_p, w1r_p, b1, h1_b, nullptr, nullptr, nullptr, N);

  // ----- layer 2 + fused pooling (h2 never leaves the CU) -----
  sage_fused_k<128, 32, true><<<(N + 31) / 32, 256, 0, stream>>>(
      h1_b, offs, perm, w2l_p, w2r_p, b2, nullptr, batch, gsum, gmax, N);

  // ----- head -----
  head_k<<<GRAPHS, 128, 0, stream>>>(gsum, gmax, gstart, W3, b3, W4, b4, (float*)d_out);
}

// Round 14
// 107.397 us; speedup vs baseline: 1.1563x; 1.0723x over previous
//
#include <hip/hip_runtime.h>
#include <math.h>

// Problem constants: N=50000, E=800000, IN=64, H=128, OUT=64, G=64
constexpr int HDIM = 128;
constexpr int GRAPHS = 64;
constexpr int OUTD = 64;
constexpr int BK_SHIFT = 7;            // bucket = dst >> 7 (128 nodes/bucket)
constexpr int BK_NODES = 1 << BK_SHIFT;
constexpr int BK_CAP   = 2560;         // max edges per bucket (mean 2048, +11 sigma)

typedef __attribute__((ext_vector_type(8))) short bf16x8;
typedef __attribute__((ext_vector_type(8))) unsigned short us8;
typedef __attribute__((ext_vector_type(4))) unsigned short us4;
typedef __attribute__((ext_vector_type(4))) float f32x4;

__device__ inline float bf2f(unsigned short u) {
  return __uint_as_float(((unsigned int)u) << 16);
}
__device__ inline unsigned short f2bf(float x) {
  unsigned int u = __float_as_uint(x);
  return (unsigned short)((u + 0x7FFF + ((u >> 16) & 1)) >> 16);  // RNE
}

__device__ inline void atomicMaxF(float* addr, float v) {
  if (v >= 0.0f) atomicMax((int*)addr, __float_as_int(v));
  else           atomicMin((unsigned int*)addr, __float_as_uint(v));
}

// ---------------- prep: pack weights + convert x + zero gcnt + init pools + gstart ----------------
__device__ inline void pack_body(const float* __restrict__ W, unsigned short* __restrict__ P,
                                 int K, int tid) {
  int lane = tid & 63, frag = tid >> 6;
  int t = frag >> 3, ct = frag & 7;
  int kb = t * 32 + (lane >> 4) * 8;
  int col = ct * 16 + (lane & 15);
  us8 o;
#pragma unroll
  for (int i = 0; i < 8; i++) o[i] = f2bf(W[(size_t)(kb + i) * HDIM + col]);
  *(us8*)(P + (size_t)tid * 8) = o;
}

__global__ __launch_bounds__(256) void prep_k(
    const float* __restrict__ x, unsigned short* __restrict__ x_b, int nx4,
    const float* __restrict__ W1l, const float* __restrict__ W1r,
    const float* __restrict__ W2l, const float* __restrict__ W2r,
    unsigned short* w1l_p, unsigned short* w1r_p,
    unsigned short* w2l_p, unsigned short* w2r_p,
    int* __restrict__ gcnt, int nbk,
    float* __restrict__ gsum, float* __restrict__ gmax,
    const int* __restrict__ batch, int* __restrict__ gstart, int n) {
  const int b = blockIdx.x, t = threadIdx.x;
  if (b < 4)        pack_body(W1l, w1l_p, 64,  b * 256 + t);
  else if (b < 8)   pack_body(W1r, w1r_p, 64,  (b - 4) * 256 + t);
  else if (b < 16)  pack_body(W2l, w2l_p, 128, (b - 8) * 256 + t);
  else if (b < 24)  pack_body(W2r, w2r_p, 128, (b - 16) * 256 + t);
  else if (b == 24) { for (int i = t; i < nbk; i += 256) gcnt[i] = 0; }
  else if (b == 25) {
    for (int i = t; i < GRAPHS * HDIM; i += 256) { gsum[i] = 0.0f; gmax[i] = -INFINITY; }
  } else if (b == 26) {
    if (t <= GRAPHS) {
      int g = t;
      int lo = 0, hi = n;
      while (lo < hi) {
        int mid = (lo + hi) >> 1;
        if (batch[mid] < g) lo = mid + 1; else hi = mid;
      }
      gstart[g] = (g == GRAPHS) ? n : lo;
    }
  } else {
    for (int i = (b - 27) * 256 + t; i < nx4; i += 256 * 256) {
      float4 v = ((const float4*)x)[i];
      us4 o = { f2bf(v.x), f2bf(v.y), f2bf(v.z), f2bf(v.w) };
      *((us4*)x_b + i) = o;
    }
  }
}

// ---------------- phase 1: radix-partition edges into dst-buckets (packed int) ----------------
__global__ __launch_bounds__(256) void partition_k(const int* __restrict__ src,
                                                   const int* __restrict__ dst,
                                                   int* __restrict__ gcnt,
                                                   int* __restrict__ ebuf,
                                                   int E, int nbk) {
  __shared__ int hist[512];
  __shared__ int lcur[512];
  __shared__ int rbase[512];
  const int t = threadIdx.x;
  int tile = (E + gridDim.x - 1) / gridDim.x;
  int e0 = blockIdx.x * tile;
  int e1 = min(E, e0 + tile);
  for (int i = t; i < 512; i += 256) { hist[i] = 0; lcur[i] = 0; }
  __syncthreads();
  for (int e = e0 + t; e < e1; e += 256)
    atomicAdd(&hist[dst[e] >> BK_SHIFT], 1);
  __syncthreads();
  for (int b = t; b < nbk; b += 256)
    if (hist[b] > 0) rbase[b] = atomicAdd(&gcnt[b], hist[b]);
  __syncthreads();
  for (int e = e0 + t; e < e1; e += 256) {
    int d = dst[e];
    int b = d >> BK_SHIFT;
    int slot = rbase[b] + atomicAdd(&lcur[b], 1);
    if (slot < BK_CAP)
      ebuf[(size_t)b * BK_CAP + slot] = ((d & (BK_NODES - 1)) << 20) | src[e];
  }
}

// ---------------- phase 2: per-bucket perm + offs build (self-computed bbase) ----------------
__global__ __launch_bounds__(256) void perm_build_k(const int* __restrict__ ebuf,
                                                    const int* __restrict__ gcnt,
                                                    int* __restrict__ offs,
                                                    int* __restrict__ perm, int n) {
  __shared__ int st[BK_CAP];
  __shared__ int perm_st[BK_CAP];
  __shared__ int nh[BK_NODES];
  __shared__ int excl_s[BK_NODES];
  __shared__ int lc[BK_NODES];
  __shared__ int psum[256];
  const int b = blockIdx.x;
  const int t = threadIdx.x;
  const int nodeBase = b << BK_SHIFT;
  const int cnt = min(gcnt[b], BK_CAP);

  // compute bbase = sum(gcnt[0..b-1]) block-locally (391 ints, L2-hot)
  int part = 0;
  for (int i = t; i < b; i += 256) part += gcnt[i];
  psum[t] = part;
  for (int i = t; i < BK_NODES; i += 256) nh[i] = 0;
  __syncthreads();
#pragma unroll
  for (int s2 = 128; s2 > 0; s2 >>= 1) {
    if (t < s2) psum[t] += psum[t + s2];
    __syncthreads();
  }
  const int bb = psum[0];

  for (int i = t; i < cnt; i += 256) {
    int e = ebuf[(size_t)b * BK_CAP + i];
    st[i] = e;
    atomicAdd(&nh[e >> 20], 1);
  }
  __syncthreads();
  if (t < 64) {
    int v0 = nh[t];
    int incl = v0;
#pragma unroll
    for (int d = 1; d < 64; d <<= 1) {
      int u = __shfl_up(incl, d, 64);
      if (t >= d) incl += u;
    }
    excl_s[t] = incl - v0;
    int tot0 = __shfl(incl, 63, 64);
    int v1 = nh[64 + t];
    int incl1 = v1;
#pragma unroll
    for (int d = 1; d < 64; d <<= 1) {
      int u = __shfl_up(incl1, d, 64);
      if (t >= d) incl1 += u;
    }
    excl_s[64 + t] = tot0 + incl1 - v1;
  }
  __syncthreads();
  for (int i = t; i < BK_NODES; i += 256) {
    int idx = nodeBase + i;
    if (idx <= n) offs[idx] = bb + excl_s[i];
  }
  for (int i = t; i < BK_NODES; i += 256) lc[i] = excl_s[i];
  __syncthreads();
  for (int i = t; i < cnt; i += 256) {
    int e = st[i];
    int slot = atomicAdd(&lc[e >> 20], 1);
    perm_st[slot] = e & 0xFFFFF;
  }
  __syncthreads();
  for (int i = t; i < cnt; i += 256) perm[bb + i] = perm_st[i];
}

// ---------------- fused SAGE layer: gather-mean -> LDS -> MFMA (-> optional fused pooling) ----
// ROWS rows/block, 256 thr. LDS A row stride K+24 ch. 4-way ILP gather, direct perm reads.
template<int K, int ROWS, bool POOL>
__global__ __launch_bounds__(256) void sage_fused_k(
    const unsigned short* __restrict__ feat,
    const int* __restrict__ offs, const int* __restrict__ perm,
    const unsigned short* __restrict__ B0, const unsigned short* __restrict__ B1,
    const float* __restrict__ bias, unsigned short* __restrict__ out,
    const int* __restrict__ batch, float* __restrict__ gsum, float* __restrict__ gmax,
    int n) {
  constexpr int NT = K / 32;
  constexpr int C8 = K / 8;          // threads per row in gather phase
  constexpr int SR = K + 24;         // LDS A row stride (ch)
  constexpr int RPP = 256 / C8;      // rows covered per gather pass
  constexpr int PASSES = (ROWS + RPP - 1) / RPP;
  constexpr int RT = ROWS / 16;      // row tiles
  constexpr int WPR = 4 / RT;        // waves per row tile
  constexpr int CTW = 8 / WPR;       // col tiles per wave
  constexpr int PSR = HDIM + 8;      // pool tile row stride (ch)
  __shared__ unsigned short a_lds[ROWS * SR];
  __shared__ int batch_s[ROWS];
  const int t = threadIdx.x;
  const int rowBase = blockIdx.x * ROWS;

  // ---- gather phase: mean over neighbors (4-way ILP), write LDS A-tile ----
#pragma unroll
  for (int p = 0; p < PASSES; p++) {
    int lr = p * RPP + t / C8;
    int c8 = t % C8;
    int row = rowBase + lr;
    if (lr < ROWS && row < n) {
      int s = offs[row], e = offs[row + 1];
      float acc[8] = {0.f, 0.f, 0.f, 0.f, 0.f, 0.f, 0.f, 0.f};
      const unsigned short* fb = feat + c8 * 8;
      int j = s;
      for (; j + 3 < e; j += 4) {
        int r0 = perm[j], r1 = perm[j + 1], r2 = perm[j + 2], r3 = perm[j + 3];
        us8 v0 = *(const us8*)(fb + (size_t)r0 * K);
        us8 v1 = *(const us8*)(fb + (size_t)r1 * K);
        us8 v2 = *(const us8*)(fb + (size_t)r2 * K);
        us8 v3 = *(const us8*)(fb + (size_t)r3 * K);
#pragma unroll
        for (int q = 0; q < 8; q++)
          acc[q] += (bf2f(v0[q]) + bf2f(v1[q])) + (bf2f(v2[q]) + bf2f(v3[q]));
      }
      for (; j < e; j++) {
        int r = perm[j];
        us8 v = *(const us8*)(fb + (size_t)r * K);
#pragma unroll
        for (int q = 0; q < 8; q++) acc[q] += bf2f(v[q]);
      }
      float sc = 1.0f / fmaxf((float)(e - s), 1.0f);
      us8 o;
#pragma unroll
      for (int q = 0; q < 8; q++) o[q] = f2bf(acc[q] * sc);
      *(us8*)(a_lds + lr * SR + c8 * 8) = o;
    }
  }
  if (POOL && t < ROWS) {
    int row = rowBase + t;
    batch_s[t] = (row < n) ? batch[row] : -1;
  }
  __syncthreads();

  // ---- MFMA phase ----
  const int lane = t & 63;
  const int w = t >> 6;
  const int rh = w / WPR;            // row tile
  const int cw = w % WPR;            // col group
  const int row0 = rowBase + rh * 16;
  const int l16 = lane & 15, lhi = lane >> 4;
  f32x4 acc[CTW];
#pragma unroll
  for (int cc = 0; cc < CTW; cc++) acc[cc] = (f32x4){0.f, 0.f, 0.f, 0.f};
  const unsigned short* al = a_lds + (rh * 16 + l16) * SR + lhi * 8;
  const unsigned short* ag = feat + (size_t)min(row0 + l16, n - 1) * K + lhi * 8;
#pragma unroll
  for (int t2 = 0; t2 < NT; t2++) {
    bf16x8 afA = *(const bf16x8*)(al + t2 * 32);
    bf16x8 afS = *(const bf16x8*)(ag + t2 * 32);
#pragma unroll
    for (int cc = 0; cc < CTW; cc++) {
      int ct = cw * CTW + cc;
      bf16x8 b0 = *(const bf16x8*)(B0 + ((size_t)(t2 * 8 + ct) * 64 + lane) * 8);
      acc[cc] = __builtin_amdgcn_mfma_f32_16x16x32_bf16(afA, b0, acc[cc], 0, 0, 0);
      bf16x8 b1 = *(const bf16x8*)(B1 + ((size_t)(t2 * 8 + ct) * 64 + lane) * 8);
      acc[cc] = __builtin_amdgcn_mfma_f32_16x16x32_bf16(afS, b1, acc[cc], 0, 0, 0);
    }
  }

  if constexpr (!POOL) {
    // epilogue: bias + ELU + global store
#pragma unroll
    for (int cc = 0; cc < CTW; cc++) {
      int col = (cw * CTW + cc) * 16 + l16;
      float bs = bias[col];
#pragma unroll
      for (int i = 0; i < 4; i++) {
        int row = row0 + lhi * 4 + i;
        if (row < n) {
          float v = acc[cc][i] + bs;
          v = (v > 0.f) ? v : expm1f(v);
          out[(size_t)row * HDIM + col] = f2bf(v);
        }
      }
    }
  } else {
    // epilogue: bias + ELU into reused LDS pool tile, then segmented per-graph reduce
    __syncthreads();  // all a_lds MFMA reads complete before overwrite
    unsigned short* ptile = a_lds;  // [ROWS][PSR], fits in a_lds for K=128
#pragma unroll
    for (int cc = 0; cc < CTW; cc++) {
      int col = (cw * CTW + cc) * 16 + l16;
      float bs = bias[col];
#pragma unroll
      for (int i = 0; i < 4; i++) {
        int rl = rh * 16 + lhi * 4 + i;
        float v = acc[cc][i] + bs;
        v = (v > 0.f) ? v : expm1f(v);
        ptile[rl * PSR + col] = f2bf(v);
      }
    }
    __syncthreads();
    // pool scan: thread (c = t&127, half = t>>7) scans ROWS/2 rows of its channel
    int c = t & 127;
    int half = t >> 7;
    float sum = 0.0f, mx = -INFINITY;
    int gc = -1;
    for (int r = half * (ROWS / 2); r < (half + 1) * (ROWS / 2); r++) {
      int g = batch_s[r];
      if (g < 0) continue;
      float v = bf2f(ptile[r * PSR + c]);
      if (g != gc) {
        if (gc >= 0) {
          atomicAdd(&gsum[gc * HDIM + c], sum);
          atomicMaxF(&gmax[gc * HDIM + c], mx);
        }
        gc = g; sum = 0.0f; mx = -INFINITY;
      }
      sum += v;
      mx = fmaxf(mx, v);
    }
    if (gc >= 0) {
      atomicAdd(&gsum[gc * HDIM + c], sum);
      atomicMaxF(&gmax[gc * HDIM + c], mx);
    }
  }
}

// ---------------- MLP head (f32) ----------------
__global__ __launch_bounds__(128) void head_k(
    const float* __restrict__ gsum, const float* __restrict__ gmax,
    const int* __restrict__ gstart,
    const float* __restrict__ W3, const float* __restrict__ b3,
    const float* __restrict__ W4, const float* __restrict__ b4,
    float* __restrict__ out) {
  __shared__ float pool_s[HDIM];
  __shared__ float t1_s[HDIM];
  int g = blockIdx.x, c = threadIdx.x;
  float cntf = (float)(gstart[g + 1] - gstart[g]);
  float ic = 1.0f / fmaxf(cntf, 1.0f);
  pool_s[c] = gsum[g * HDIM + c] * ic + gmax[g * HDIM + c];
  __syncthreads();
  float acc = b3[c];
  for (int k = 0; k < HDIM; k++) acc += pool_s[k] * W3[k * HDIM + c];
  t1_s[c] = fmaxf(acc, 0.0f);
  __syncthreads();
  if (c < OUTD) {
    float acc2 = b4[c];
    for (int k = 0; k < HDIM; k++) acc2 += t1_s[k] * W4[k * OUTD + c];
    out[g * OUTD + c] = acc2;
  }
}

extern "C" void kernel_launch(void* const* d_in, const int* in_sizes, int n_in,
                              void* d_out, int out_size, void* d_ws, size_t ws_size,
                              hipStream_t stream) {
  const float* x     = (const float*)d_in[0];
  const int*   ei    = (const int*)d_in[1];
  const int*   batch = (const int*)d_in[2];
  const float* W1l = (const float*)d_in[3];
  const float* W1r = (const float*)d_in[4];
  const float* b1  = (const float*)d_in[5];
  const float* W2l = (const float*)d_in[6];
  const float* W2r = (const float*)d_in[7];
  const float* b2  = (const float*)d_in[8];
  const float* W3  = (const float*)d_in[9];
  const float* b3  = (const float*)d_in[10];
  const float* W4  = (const float*)d_in[11];
  const float* b4  = (const float*)d_in[12];

  const int N  = in_sizes[2];          // 50000
  const int E  = in_sizes[1] / 2;      // 800000
  const int IN = in_sizes[0] / N;      // 64
  const int* src = ei;
  const int* dst = ei + E;
  const int NBK = (N + BK_NODES - 1) / BK_NODES;  // 391 buckets

  // workspace layout
  char* ws = (char*)d_ws;
  size_t off = 0;
  auto alloc = [&](size_t bytes) { void* p = ws + off; off += (bytes + 255) & ~(size_t)255; return p; };
  int*  offs  = (int*)alloc((size_t)(N + 1) * 4);
  int*  perm  = (int*)alloc((size_t)E * 4);
  int*  gcnt  = (int*)alloc((size_t)NBK * 4);
  int*  ebuf  = (int*)alloc((size_t)NBK * BK_CAP * 4);
  unsigned short* x_b   = (unsigned short*)alloc((size_t)N * IN * 2);
  unsigned short* h1_b  = (unsigned short*)alloc((size_t)N * HDIM * 2);
  unsigned short* w1l_p = (unsigned short*)alloc((size_t)IN * HDIM * 2);
  unsigned short* w1r_p = (unsigned short*)alloc((size_t)IN * HDIM * 2);
  unsigned short* w2l_p = (unsigned short*)alloc((size_t)HDIM * HDIM * 2);
  unsigned short* w2r_p = (unsigned short*)alloc((size_t)HDIM * HDIM * 2);
  float* gsum = (float*)alloc((size_t)GRAPHS * HDIM * 4);
  float* gmax = (float*)alloc((size_t)GRAPHS * HDIM * 4);
  int* gstart = (int*)alloc((size_t)(GRAPHS + 1) * 4);
  (void)ws_size; (void)n_in; (void)out_size;

  // ---- prep: pack weights + convert x + zero gcnt + init pools + gstart (one launch) ----
  prep_k<<<283, 256, 0, stream>>>(x, x_b, N * IN / 4, W1l, W1r, W2l, W2r,
                                  w1l_p, w1r_p, w2l_p, w2r_p, gcnt, NBK, gsum, gmax,
                                  batch, gstart, N);

  // ---- build CSR via radix partition (2 kernels) ----
  partition_k<<<256, 256, 0, stream>>>(src, dst, gcnt, ebuf, E, NBK);
  perm_build_k<<<NBK, 256, 0, stream>>>(ebuf, gcnt, offs, perm, N);

  // ----- layer 1 (fused gather + GEMM): h1 = elu(mean(x_nbr)@W1l + x@W1r + b1) -----
  sage_fused_k<64, 32, false><<<(N + 31) / 32, 256, 0, stream>>>(
      x_b, offs, perm, w1l_p, w1r_p, b1, h1_b, nullptr, nullptr, nullptr, N);

  // ----- layer 2 + fused pooling (h2 never leaves the CU) -----
  sage_fused_k<128, 32, true><<<(N + 31) / 32, 256, 0, stream>>>(
      h1_b, offs, perm, w2l_p, w2r_p, b2, nullptr, batch, gsum, gmax, N);

  // ----- head -----
  head_k<<<GRAPHS, 128, 0, stream>>>(gsum, gmax, gstart, W3, b3, W4, b4, (float*)d_out);
}